// Round 4
// baseline (2913.382 us; speedup 1.0000x reference)
//
#include <hip/hip_runtime.h>
#include <math.h>

// Problem constants
//   B=4, NB=2048, NA=NC=1024, D=1024, E=8, H=16, HD=64, TOP_K=2
// All-fp32 implementation (no MFMA): top-2 routing makes numerics precision-critical.
// R3 lesson: NO lambdas capturing register arrays in hot kernels (scratch spills).
// R4: attention restructured to 128x128 tiles / 8x8 frags / k-split PV => ~1 LDS byte
// per FMA (was ~3) since attn was LDS-BW-bound, not VALU-bound.

// ----------------------------------------------------------------------------
__global__ void zero_k(double* p) {
    if (threadIdx.x < 8) p[threadIdx.x] = 0.0;
}

// ----------------------------------------------------------------------------
// sinusoidal time embedding: emb[b][0:512]=sin(t*freq), [512:1024]=cos(t*freq)
__global__ void emb_k(const int* __restrict__ t, float* __restrict__ emb) {
    int b = blockIdx.x;
    int j = threadIdx.x; // 0..511
    float x1 = (float)(-9.210340371976184) * (float)j;  // -log(10000) * j  (fp32, like np)
    float x2 = x1 / 511.0f;
    float freq = (float)exp((double)x2);
    float tf = (float)t[b];
    float arg = tf * freq;                               // fp32 product, like np
    emb[b * 1024 + j]       = (float)sin((double)arg);
    emb[b * 1024 + 512 + j] = (float)cos((double)arg);
}

// ----------------------------------------------------------------------------
// tiny FC for the time-embedding MLP
__global__ void te_fc_k(const float* __restrict__ in, const float* __restrict__ W,
                        const float* __restrict__ bias, float* __restrict__ out,
                        int K, int N, int do_silu) {
    int b = blockIdx.x;
    int wv = threadIdx.x >> 6, lane = threadIdx.x & 63;
    const float* inb = in + (size_t)b * K;
    int n0 = blockIdx.y * 16 + wv * 4;
    for (int q = 0; q < 4; q++) {
        int n = n0 + q;
        const float* wr = W + (size_t)n * K;
        float acc = 0.f;
        for (int c = lane * 4; c < K; c += 256) {
            float4 a  = *(const float4*)(inb + c);
            float4 w4 = *(const float4*)(wr + c);
            acc += a.x * w4.x + a.y * w4.y + a.z * w4.z + a.w * w4.w;
        }
#pragma unroll
        for (int off = 1; off < 64; off <<= 1) acc += __shfl_xor(acc, off, 64);
        if (lane == 0) {
            float x = acc + bias[n];
            out[(size_t)b * N + n] = do_silu ? (x / (1.0f + expf(-x))) : x;
        }
    }
}

// ----------------------------------------------------------------------------
// fp32 GEMM: C[orow(r), col] = dot(A[r,:K], W[col,:K]) + bias[col]  (W row-major (N,K))
// 128x128 tile, BK=16, 256 threads, split 4+4 fragments, single LDS buffer +
// register prefetch of the next chunk (explicit float4 locals, macro-expanded).

#define GEMM_LOAD_CHUNK(kk_) do {                                              \
    int kk = (kk_);                                                            \
    const float* Asel = A0; int colbase = kk;                                  \
    int ar0 = row0 + m0, ar1 = row0 + m1;                                      \
    if (GATE) {                                                                \
        int seg = kk >> 10;                                                    \
        if (seg == 1) Asel = A1; else if (seg == 2) Asel = A2;                 \
        colbase = kk & 1023;                                                   \
        if (seg == 2) { ar0 = (row0 + m0) >> 11; ar1 = (row0 + m1) >> 11; }    \
    }                                                                          \
    rA0 = *(const float4*)(Asel + (size_t)ar0 * 1024 + colbase + k4);          \
    rA1 = *(const float4*)(Asel + (size_t)ar1 * 1024 + colbase + k4);          \
    rB0 = *(const float4*)(W + (size_t)(col0 + m0) * K + kk + k4);             \
    rB1 = *(const float4*)(W + (size_t)(col0 + m1) * K + kk + k4);             \
} while (0)

#define GEMM_STORE_CHUNK() do {                                                \
    As[k4 + 0][m0] = rA0.x; As[k4 + 1][m0] = rA0.y;                            \
    As[k4 + 2][m0] = rA0.z; As[k4 + 3][m0] = rA0.w;                            \
    As[k4 + 0][m1] = rA1.x; As[k4 + 1][m1] = rA1.y;                            \
    As[k4 + 2][m1] = rA1.z; As[k4 + 3][m1] = rA1.w;                            \
    Bs[k4 + 0][m0] = rB0.x; Bs[k4 + 1][m0] = rB0.y;                            \
    Bs[k4 + 2][m0] = rB0.z; Bs[k4 + 3][m0] = rB0.w;                            \
    Bs[k4 + 0][m1] = rB1.x; Bs[k4 + 1][m1] = rB1.y;                            \
    Bs[k4 + 2][m1] = rB1.z; Bs[k4 + 3][m1] = rB1.w;                            \
} while (0)

template<bool GATE, bool RELU>
__global__ __launch_bounds__(256, 2)
void gemm_k(const float* __restrict__ A0, const float* __restrict__ A1,
            const float* __restrict__ A2,
            const float* __restrict__ W, const float* __restrict__ bias,
            float* __restrict__ C, int K,
            int out_rshift, int out_stride, int out_base, size_t colSegStride)
{
    __shared__ float As[16][132];
    __shared__ float Bs[16][132];
    const int tid = threadIdx.x;
    const int tx = tid & 15, ty = tid >> 4;
    const int row0 = blockIdx.x * 128;
    const int col0 = blockIdx.y * 128;
    const int m0 = tid >> 2;          // 0..63
    const int m1 = m0 + 64;           // 64..127
    const int k4 = (tid & 3) * 4;

    float acc[8][8];
#pragma unroll
    for (int i = 0; i < 8; i++)
#pragma unroll
        for (int j = 0; j < 8; j++) acc[i][j] = 0.f;

    float4 rA0, rA1, rB0, rB1;
    GEMM_LOAD_CHUNK(0);

    const int nch = K >> 4;
    for (int c = 0; c < nch; c++) {
        GEMM_STORE_CHUNK();
        __syncthreads();
        if (c + 1 < nch) GEMM_LOAD_CHUNK((c + 1) << 4);   // in flight during compute
#pragma unroll
        for (int k = 0; k < 16; k++) {
            float4 a0 = *(const float4*)&As[k][ty * 4];
            float4 a1 = *(const float4*)&As[k][64 + ty * 4];
            float4 b0 = *(const float4*)&Bs[k][tx * 4];
            float4 b1 = *(const float4*)&Bs[k][64 + tx * 4];
            float av[8] = {a0.x, a0.y, a0.z, a0.w, a1.x, a1.y, a1.z, a1.w};
            float bv[8] = {b0.x, b0.y, b0.z, b0.w, b1.x, b1.y, b1.z, b1.w};
#pragma unroll
            for (int i = 0; i < 8; i++)
#pragma unroll
                for (int j = 0; j < 8; j++)
                    acc[i][j] += av[i] * bv[j];
        }
        __syncthreads();
    }

#pragma unroll
    for (int i = 0; i < 8; i++) {
        int rr = row0 + ((i < 4) ? (ty * 4 + i) : (64 + ty * 4 + i - 4));
        int orow = out_base + (rr >> out_rshift) * out_stride + (rr & ((1 << out_rshift) - 1));
#pragma unroll
        for (int jj = 0; jj < 2; jj++) {
            int cglob = col0 + jj * 64 + tx * 4;
            float* Cb = C + (size_t)(cglob >> 10) * colSegStride + (cglob & 1023);
            float4 v;
            v.x = acc[i][jj * 4 + 0] + bias[cglob + 0];
            v.y = acc[i][jj * 4 + 1] + bias[cglob + 1];
            v.z = acc[i][jj * 4 + 2] + bias[cglob + 2];
            v.w = acc[i][jj * 4 + 3] + bias[cglob + 3];
            if (RELU) {
                v.x = fmaxf(v.x, 0.f); v.y = fmaxf(v.y, 0.f);
                v.z = fmaxf(v.z, 0.f); v.w = fmaxf(v.w, 0.f);
            }
            *(float4*)(Cb + (size_t)orow * 1024) = v;
        }
    }
}

// ----------------------------------------------------------------------------
// flash-style fp32 attention v2: 128q x 128k tiles, 8x8 QK frags (4+4 split),
// P via LDS [q][kphys] with +2 half-panel pad, PV with 8q x 8d frags and a
// k-half split across lanes (kz = tx>>3) reduced once at the end.
// LDS 137 KB -> 1 block/CU (4 waves). HD=64, S=2048, scale folded into Q.
__global__ __launch_bounds__(256, 1)
void attn_k(const float* __restrict__ Q, const float* __restrict__ Kb,
            const float* __restrict__ Vb, float* __restrict__ O)
{
    __shared__ float Qs[64][132];     // [d][q], Q pre-scaled by 1/8
    __shared__ float U[128 * 132];    // phase1: K [d][k] rows 0..63; phase2: P [q][kphys]
    __shared__ float Vs[132][68];     // [kphys][d], kphys = k + 2*(k>>6)
    const int tid = threadIdx.x;
    const int tx = tid & 15, ty = tid >> 4;
    const int dg = tx & 7, kz = tx >> 3;
    const int bh = blockIdx.x;            // 0..63
    const int b = bh >> 4, h = bh & 15;
    const int q0 = blockIdx.y * 128;
    const size_t qbase  = ((size_t)(b * 2048 + q0)) * 1024 + h * 64;
    const size_t kvbase = ((size_t)(b * 2048)) * 1024 + h * 64;

    // stage Q (128 x 64) transposed, scaled by 0.125 (exact pow2)
#pragma unroll
    for (int tp = 0; tp < 8; tp++) {
        int idx = tid + tp * 256;
        int qr = idx >> 4;                // 0..127
        int d4 = (idx & 15) * 4;
        float4 v = *(const float4*)(Q + qbase + (size_t)qr * 1024 + d4);
        Qs[d4 + 0][qr] = v.x * 0.125f; Qs[d4 + 1][qr] = v.y * 0.125f;
        Qs[d4 + 2][qr] = v.z * 0.125f; Qs[d4 + 3][qr] = v.w * 0.125f;
    }
    // prefetch K/V tile 0 into registers
    float4 kr[8], vr[8];
#pragma unroll
    for (int tp = 0; tp < 8; tp++) {
        int idx = tid + tp * 256;
        int krw = idx >> 4;
        int d4 = (idx & 15) * 4;
        kr[tp] = *(const float4*)(Kb + kvbase + (size_t)krw * 1024 + d4);
        vr[tp] = *(const float4*)(Vb + kvbase + (size_t)krw * 1024 + d4);
    }
    float o2[8][8] = {};
    float mrow[8], lrow[8];
#pragma unroll
    for (int i = 0; i < 8; i++) { mrow[i] = -INFINITY; lrow[i] = 0.f; }

    for (int kt = 0; kt < 16; kt++) {
        // staging stores (K transposed into U rows 0..63, V direct into Vs)
#pragma unroll
        for (int tp = 0; tp < 8; tp++) {
            int idx = tid + tp * 256;
            int krw = idx >> 4;
            int d4 = (idx & 15) * 4;
            U[(d4 + 0) * 132 + krw] = kr[tp].x;
            U[(d4 + 1) * 132 + krw] = kr[tp].y;
            U[(d4 + 2) * 132 + krw] = kr[tp].z;
            U[(d4 + 3) * 132 + krw] = kr[tp].w;
            *(float4*)&Vs[krw + 2 * (krw >> 6)][d4] = vr[tp];
        }
        __syncthreads();   // staging (and, first iter, Qs) visible
        if (kt + 1 < 16) {
#pragma unroll
            for (int tp = 0; tp < 8; tp++) {
                int idx = tid + tp * 256;
                int krw = idx >> 4;
                int d4 = (idx & 15) * 4;
                size_t gofs = kvbase + (size_t)((kt + 1) * 128 + krw) * 1024 + d4;
                kr[tp] = *(const float4*)(Kb + gofs);
                vr[tp] = *(const float4*)(Vb + gofs);
            }
        }
        // QK^T: s[8 q][8 k], q rows ty*4 & 64+ty*4, k cols tx*4 & 64+tx*4
        float s[8][8] = {};
#pragma unroll 4
        for (int d = 0; d < 64; d++) {
            const float* Ud = &U[d * 132];
            float4 qa0 = *(const float4*)&Qs[d][ty * 4];
            float4 qa1 = *(const float4*)&Qs[d][64 + ty * 4];
            float4 ka0 = *(const float4*)&Ud[tx * 4];
            float4 ka1 = *(const float4*)&Ud[64 + tx * 4];
            float qv[8] = {qa0.x, qa0.y, qa0.z, qa0.w, qa1.x, qa1.y, qa1.z, qa1.w};
            float kv[8] = {ka0.x, ka0.y, ka0.z, ka0.w, ka1.x, ka1.y, ka1.z, ka1.w};
#pragma unroll
            for (int i = 0; i < 8; i++)
#pragma unroll
                for (int j = 0; j < 8; j++)
                    s[i][j] += qv[i] * kv[j];
        }
        __syncthreads();   // all QK reads done -> U reusable for P
        // online softmax (row stats across 16 tx lanes) + P write
#pragma unroll
        for (int i = 0; i < 8; i++) {
            float rmax = s[i][0];
#pragma unroll
            for (int j = 1; j < 8; j++) rmax = fmaxf(rmax, s[i][j]);
#pragma unroll
            for (int off = 1; off < 16; off <<= 1)
                rmax = fmaxf(rmax, __shfl_xor(rmax, off, 64));
            float mnew = fmaxf(mrow[i], rmax);
            float corr = expf(mrow[i] - mnew);
            float psum = 0.f;
#pragma unroll
            for (int j = 0; j < 8; j++) { float p = expf(s[i][j] - mnew); s[i][j] = p; psum += p; }
#pragma unroll
            for (int off = 1; off < 16; off <<= 1)
                psum += __shfl_xor(psum, off, 64);
            lrow[i] = lrow[i] * corr + psum;
#pragma unroll
            for (int j = 0; j < 8; j++) o2[i][j] *= corr;
            mrow[i] = mnew;
            int prow = (i < 4) ? (ty * 4 + i) : (64 + ty * 4 + i - 4);
            *(float4*)&U[prow * 132 + tx * 4]      = make_float4(s[i][0], s[i][1], s[i][2], s[i][3]);
            *(float4*)&U[prow * 132 + 66 + tx * 4] = make_float4(s[i][4], s[i][5], s[i][6], s[i][7]);
        }
        __syncthreads();   // P visible
        // PV: this lane handles k-half kz (64 keys), d cols dg*4 and 32+dg*4
#pragma unroll 2
        for (int kq = 0; kq < 16; kq++) {
            int kc = kz * 66 + kq * 4;     // phys col in U == phys row in Vs
            float4 p0 = *(const float4*)&U[(ty * 4 + 0) * 132 + kc];
            float4 p1 = *(const float4*)&U[(ty * 4 + 1) * 132 + kc];
            float4 p2 = *(const float4*)&U[(ty * 4 + 2) * 132 + kc];
            float4 p3 = *(const float4*)&U[(ty * 4 + 3) * 132 + kc];
            float4 p4 = *(const float4*)&U[(64 + ty * 4 + 0) * 132 + kc];
            float4 p5 = *(const float4*)&U[(64 + ty * 4 + 1) * 132 + kc];
            float4 p6 = *(const float4*)&U[(64 + ty * 4 + 2) * 132 + kc];
            float4 p7 = *(const float4*)&U[(64 + ty * 4 + 3) * 132 + kc];
            float4 va[4], vb2[4];
#pragma unroll
            for (int l = 0; l < 4; l++) {
                va[l]  = *(const float4*)&Vs[kc + l][dg * 4];
                vb2[l] = *(const float4*)&Vs[kc + l][32 + dg * 4];
            }
            float pa[8][4] = {
                {p0.x, p0.y, p0.z, p0.w}, {p1.x, p1.y, p1.z, p1.w},
                {p2.x, p2.y, p2.z, p2.w}, {p3.x, p3.y, p3.z, p3.w},
                {p4.x, p4.y, p4.z, p4.w}, {p5.x, p5.y, p5.z, p5.w},
                {p6.x, p6.y, p6.z, p6.w}, {p7.x, p7.y, p7.z, p7.w}};
#pragma unroll
            for (int i = 0; i < 8; i++) {
#pragma unroll
                for (int l = 0; l < 4; l++) {
                    float pv = pa[i][l];
                    o2[i][0] += pv * va[l].x;  o2[i][1] += pv * va[l].y;
                    o2[i][2] += pv * va[l].z;  o2[i][3] += pv * va[l].w;
                    o2[i][4] += pv * vb2[l].x; o2[i][5] += pv * vb2[l].y;
                    o2[i][6] += pv * vb2[l].z; o2[i][7] += pv * vb2[l].w;
                }
            }
        }
        __syncthreads();   // PV done -> U/Vs reusable next iteration
    }
    // reduce the two k-halves (lane xor 8 flips kz) and store
#pragma unroll
    for (int i = 0; i < 8; i++) {
#pragma unroll
        for (int j = 0; j < 8; j++)
            o2[i][j] += __shfl_xor(o2[i][j], 8, 64);
        if (kz == 0) {
            float invl = 1.0f / lrow[i];
            int r = q0 + ((i < 4) ? (ty * 4 + i) : (64 + ty * 4 + i - 4));
            float* orow = O + ((size_t)(b * 2048 + r)) * 1024 + h * 64;
            float4 A, Bv;
            A.x = o2[i][0] * invl; A.y = o2[i][1] * invl;
            A.z = o2[i][2] * invl; A.w = o2[i][3] * invl;
            Bv.x = o2[i][4] * invl; Bv.y = o2[i][5] * invl;
            Bv.z = o2[i][6] * invl; Bv.w = o2[i][7] * invl;
            *(float4*)(orow + dg * 4) = A;
            *(float4*)(orow + 32 + dg * 4) = Bv;
        }
    }
}

// ----------------------------------------------------------------------------
// layernorm(X + T) * g + b, one block per row of 1024
__global__ __launch_bounds__(256)
void ln_k(const float* __restrict__ X, const float* __restrict__ T,
          const float* __restrict__ g, const float* __restrict__ bta,
          float* __restrict__ out)
{
    __shared__ float red[8];
    int r = blockIdx.x, tid = threadIdx.x;
    size_t base = (size_t)r * 1024 + tid * 4;
    float4 x  = *(const float4*)(X + base);
    float4 tk = *(const float4*)(T + base);
    x.x += tk.x; x.y += tk.y; x.z += tk.z; x.w += tk.w;
    float s = x.x + x.y + x.z + x.w;
#pragma unroll
    for (int off = 1; off < 64; off <<= 1) s += __shfl_xor(s, off, 64);
    int wv = tid >> 6;
    if ((tid & 63) == 0) red[wv] = s;
    __syncthreads();
    float mu = (red[0] + red[1] + red[2] + red[3]) * (1.0f / 1024.0f);
    float dx0 = x.x - mu, dx1 = x.y - mu, dx2 = x.z - mu, dx3 = x.w - mu;
    float ss = dx0 * dx0 + dx1 * dx1 + dx2 * dx2 + dx3 * dx3;
#pragma unroll
    for (int off = 1; off < 64; off <<= 1) ss += __shfl_xor(ss, off, 64);
    if ((tid & 63) == 0) red[4 + wv] = ss;
    __syncthreads();
    float var = (red[4] + red[5] + red[6] + red[7]) * (1.0f / 1024.0f);
    float inv = 1.0f / sqrtf(var + 1e-5f);
    float4 gg = *(const float4*)(g + tid * 4);
    float4 bb = *(const float4*)(bta + tid * 4);
    float4 y;
    y.x = dx0 * inv * gg.x + bb.x;
    y.y = dx1 * inv * gg.y + bb.y;
    y.z = dx2 * inv * gg.z + bb.z;
    y.w = dx3 * inv * gg.w + bb.w;
    *(float4*)(out + base) = y;
}

// ----------------------------------------------------------------------------
// logits[r][e] = dot(hidden[r], W2[e]) + b2[e] + eb[e]; one wave per row
__global__ __launch_bounds__(256)
void logits_k(const float* __restrict__ Hd, const float* __restrict__ W2,
              const float* __restrict__ b2, const float* __restrict__ eb,
              float* __restrict__ Lg)
{
    int gw = (blockIdx.x * 256 + threadIdx.x) >> 6;  // row 0..8191
    int lane = threadIdx.x & 63;
    const float* h = Hd + (size_t)gw * 1024;
    float4 hv[4];
#pragma unroll
    for (int j = 0; j < 4; j++) hv[j] = *(const float4*)(h + j * 256 + lane * 4);
    float res[8];
#pragma unroll
    for (int e = 0; e < 8; e++) {
        const float* w = W2 + (size_t)e * 1024;
        float acc = 0.f;
#pragma unroll
        for (int j = 0; j < 4; j++) {
            float4 w4 = *(const float4*)(w + j * 256 + lane * 4);
            acc += hv[j].x * w4.x + hv[j].y * w4.y + hv[j].z * w4.z + hv[j].w * w4.w;
        }
#pragma unroll
        for (int off = 1; off < 64; off <<= 1) acc += __shfl_xor(acc, off, 64);
        res[e] = acc;
    }
    if (lane < 8) {
        float v = res[0];
#pragma unroll
        for (int e = 1; e < 8; e++) v = (lane == e) ? res[e] : v;
        Lg[(size_t)gw * 8 + lane] = v + b2[lane] + eb[lane];
    }
}

// ----------------------------------------------------------------------------
// full routing epilogue: one thread per token
__global__ __launch_bounds__(256)
void router_k(const float* __restrict__ Lg, const int* __restrict__ t,
              float* __restrict__ outp, double* __restrict__ loadAcc)
{
    __shared__ double wred[4][8];
    int tid = threadIdx.x;
    int r = blockIdx.x * 256 + tid;   // 0..8191
    int b = r >> 11;
    float tn  = (float)t[b] / 1000.0f;
    float tau = 0.5f + 1.5f * tn;
    float p[8];
    float mx = -INFINITY;
#pragma unroll
    for (int e = 0; e < 8; e++) { p[e] = Lg[(size_t)r * 8 + e] / tau; mx = fmaxf(mx, p[e]); }
    float sum = 0.f;
#pragma unroll
    for (int e = 0; e < 8; e++) { p[e] = expf(p[e] - mx); sum += p[e]; }
#pragma unroll
    for (int e = 0; e < 8; e++) p[e] = p[e] / sum;
#pragma unroll
    for (int e = 0; e < 8; e++) p[e] = 0.85f * p[e] + 0.01875f;   // (1-ALPHA)p + ALPHA/E
    float w = 0.1f + 0.1f * tn;
    float shared_p = fmaxf(p[0], w);
    float osum = 0.f;
#pragma unroll
    for (int e = 1; e < 8; e++) osum += p[e];
    float denom_o = fmaxf(osum, 1e-8f);
    float one_m = 1.0f - shared_p;
    p[0] = shared_p;
#pragma unroll
    for (int e = 1; e < 8; e++) p[e] = (p[e] / denom_o) * one_m;  // match np op order
    int i0 = 0; float v0 = p[0];
#pragma unroll
    for (int e = 1; e < 8; e++) if (p[e] > v0) { v0 = p[e]; i0 = e; }
    int i1 = -1; float v1 = -INFINITY;
#pragma unroll
    for (int e = 0; e < 8; e++) if (e != i0 && p[e] > v1) { v1 = p[e]; i1 = e; }
    float cap = 0.5f + 0.1f * tn;
    float dsp[8], capped[8], hr[8];
    float exsum = 0.f, hsum = 0.f;
#pragma unroll
    for (int e = 0; e < 8; e++) {
        float d = ((e == i0) ? v0 : 0.f) + ((e == i1) ? v1 : 0.f);
        float ex = fmaxf(d - cap, 0.f);
        float c = d - ex;
        float h = fmaxf(cap - c, 0.f);
        capped[e] = c; hr[e] = h;
        exsum += ex; hsum += h;
    }
    float hden = fmaxf(hsum, 1e-8f);
    float dsum = 0.f;
#pragma unroll
    for (int e = 0; e < 8; e++) {
        float d = capped[e] + exsum * (hr[e] / hden);
        dsp[e] = d; dsum += d;
    }
    float cden = dsum + 1e-8f;
#pragma unroll
    for (int e = 0; e < 8; e++) {
        outp[(size_t)r * 8 + e] = dsp[e];
        outp[65536 + (size_t)r * 8 + e] = dsp[e] / cden;
    }
    int lane = tid & 63, wv = tid >> 6;
#pragma unroll
    for (int e = 0; e < 8; e++) {
        double s = (double)dsp[e];
#pragma unroll
        for (int off = 1; off < 64; off <<= 1) s += __shfl_xor(s, off, 64);
        if (lane == 0) wred[wv][e] = s;
    }
    __syncthreads();
    if (tid < 8) {
        double s = wred[0][tid] + wred[1][tid] + wred[2][tid] + wred[3][tid];
        atomicAdd(&loadAcc[tid], s);
    }
}

// ----------------------------------------------------------------------------
__global__ void penalty_k(const double* __restrict__ loadAcc, float* __restrict__ outp) {
    if (threadIdx.x == 0) {
        const float thr = (float)(2048.0 / 7.0 * 1.5);  // fair * 1.5
        float pen = 0.f;
#pragma unroll
        for (int e = 1; e < 8; e++) {
            float load = (float)(loadAcc[e] / 4.0);     // mean over B
            float x = fmaxf(load - thr, 0.f);
            pen += x * x;
        }
        outp[131072] = 0.01f * pen;
    }
}

// ----------------------------------------------------------------------------
extern "C" void kernel_launch(void* const* d_in, const int* in_sizes, int n_in,
                              void* d_out, int out_size, void* d_ws, size_t ws_size,
                              hipStream_t stream)
{
    const float* tokens = (const float*)d_in[0];
    const float* outA   = (const float*)d_in[1];
    const float* outC   = (const float*)d_in[2];
    const int*   tt     = (const int*)  d_in[3];
    const float* in_w   = (const float*)d_in[4];
    const float* in_b   = (const float*)d_in[5];
    const float* op_w   = (const float*)d_in[6];
    const float* op_b   = (const float*)d_in[7];
    const float* lng    = (const float*)d_in[8];
    const float* lnb    = (const float*)d_in[9];
    const float* te_w1  = (const float*)d_in[10];
    const float* te_b1  = (const float*)d_in[11];
    const float* te_w2  = (const float*)d_in[12];
    const float* te_b2  = (const float*)d_in[13];
    const float* g_w1   = (const float*)d_in[14];
    const float* g_b1   = (const float*)d_in[15];
    const float* g_w2   = (const float*)d_in[16];
    const float* g_b2   = (const float*)d_in[17];
    const float* e_bias = (const float*)d_in[18];
    float* out = (float*)d_out;

    float* ws = (float*)d_ws;
    const size_t NM = (size_t)8192 * 1024;
    float* bq   = ws;            // q proj -> later gate hidden
    float* bk   = ws + NM;       // k proj -> later ctx_B (post-LN)
    float* bv   = ws + 2 * NM;   // v proj -> later out_proj raw
    float* bo   = ws + 3 * NM;   // attention output
    float* temb   = ws + 4 * NM;        // 4x1024
    float* embb   = temb + 4096;        // 4x1024
    float* hte    = embb + 4096;        // 4x2048
    float* logitsb = hte + 8192;        // 8192x8
    double* loads = (double*)(logitsb + 65536);  // 8 doubles

    zero_k<<<1, 64, 0, stream>>>(loads);
    emb_k<<<4, 512, 0, stream>>>(tt, embb);
    te_fc_k<<<dim3(4, 128), 256, 0, stream>>>(embb, te_w1, te_b1, hte, 1024, 2048, 1);
    te_fc_k<<<dim3(4, 64),  256, 0, stream>>>(hte,  te_w2, te_b2, temb, 2048, 1024, 0);

    // q = tokens @ wq.T + bq
    gemm_k<false, false><<<dim3(64, 8), 256, 0, stream>>>(
        tokens, nullptr, nullptr, in_w, in_b, bq, 1024, 13, 0, 0, 0);
    // k & v together (cols 0..1023 -> bk, 1024..2047 -> bv=bk+NM), per-batch concat remap
    gemm_k<false, false><<<dim3(32, 16), 256, 0, stream>>>(
        outA, nullptr, nullptr, in_w + (size_t)1024 * 1024, in_b + 1024, bk, 1024, 10, 2048, 0, NM);
    gemm_k<false, false><<<dim3(32, 16), 256, 0, stream>>>(
        outC, nullptr, nullptr, in_w + (size_t)1024 * 1024, in_b + 1024, bk, 1024, 10, 2048, 1024, NM);

    attn_k<<<dim3(64, 16), 256, 0, stream>>>(bq, bk, bv, bo);

    // out_proj (into bv, free after attention)
    gemm_k<false, false><<<dim3(64, 8), 256, 0, stream>>>(
        bo, nullptr, nullptr, op_w, op_b, bv, 1024, 13, 0, 0, 0);
    // ctx_B = LN(out_proj + tokens) into bk
    ln_k<<<8192, 256, 0, stream>>>(bv, tokens, lng, lnb, bk);
    // gate hidden = relu([tokens | ctx_B | t_emb] @ gate_w1.T + b1) into bq
    gemm_k<true, true><<<dim3(64, 8), 256, 0, stream>>>(
        tokens, bk, temb, g_w1, g_b1, bq, 3072, 13, 0, 0, 0);

    logits_k<<<2048, 256, 0, stream>>>(bq, g_w2, g_b2, e_bias, logitsb);
    router_k<<<32, 256, 0, stream>>>(logitsb, tt, out, loads);
    penalty_k<<<1, 64, 0, stream>>>(loads, out);
}

// Round 5
// 1635.603 us; speedup vs baseline: 1.7812x; 1.7812x over previous
//
#include <hip/hip_runtime.h>
#include <math.h>

// Problem constants
//   B=4, NB=2048, NA=NC=1024, D=1024, E=8, H=16, HD=64, TOP_K=2
// R3 lesson: NO lambdas capturing register arrays in hot kernels (scratch spills).
// R4 lesson: 1 wave/SIMD kills latency hiding; staging map m=tid>>2,c4=(tid&3)*4
//            is the conflict-free transpose-store pattern. attn reverted to R3.
// R5: big GEMMs moved to bf16 split-3 MFMA (hi*hi + hi*lo + lo*hi), error ~2^-16
//     relative -- below fp32-chain noise, no top-2 flip risk.

typedef __attribute__((ext_vector_type(8))) short short8;
typedef __attribute__((ext_vector_type(4))) float f32x4;

// ----------------------------------------------------------------------------
__global__ void zero_k(double* p) {
    if (threadIdx.x < 8) p[threadIdx.x] = 0.0;
}

// ----------------------------------------------------------------------------
// fp32 -> bf16 hi/lo split helpers (RNE)
__device__ inline unsigned short bf_hi(float x) {
    unsigned u = __float_as_uint(x);
    u += 0x7FFFu + ((u >> 16) & 1u);
    return (unsigned short)(u >> 16);
}
__device__ inline unsigned short bf_lo(float x, unsigned short h) {
    float hf = __uint_as_float(((unsigned)h) << 16);
    return bf_hi(x - hf);
}

__global__ __launch_bounds__(256)
void split_k(const float* __restrict__ in, unsigned short* __restrict__ hi,
             unsigned short* __restrict__ lo, int n4) {
    int i = blockIdx.x * 256 + threadIdx.x;
    if (i >= n4) return;
    float4 x = ((const float4*)in)[i];
    ushort4 h, l;
    h.x = bf_hi(x.x); l.x = bf_lo(x.x, h.x);
    h.y = bf_hi(x.y); l.y = bf_lo(x.y, h.y);
    h.z = bf_hi(x.z); l.z = bf_lo(x.z, h.z);
    h.w = bf_hi(x.w); l.w = bf_lo(x.w, h.w);
    ((ushort4*)hi)[i] = h;
    ((ushort4*)lo)[i] = l;
}

// ----------------------------------------------------------------------------
// sinusoidal time embedding
__global__ void emb_k(const int* __restrict__ t, float* __restrict__ emb) {
    int b = blockIdx.x;
    int j = threadIdx.x; // 0..511
    float x1 = (float)(-9.210340371976184) * (float)j;
    float x2 = x1 / 511.0f;
    float freq = (float)exp((double)x2);
    float tf = (float)t[b];
    float arg = tf * freq;
    emb[b * 1024 + j]       = (float)sin((double)arg);
    emb[b * 1024 + 512 + j] = (float)cos((double)arg);
}

// ----------------------------------------------------------------------------
// tiny FC for the time-embedding MLP (fp32)
__global__ void te_fc_k(const float* __restrict__ in, const float* __restrict__ W,
                        const float* __restrict__ bias, float* __restrict__ out,
                        int K, int N, int do_silu) {
    int b = blockIdx.x;
    int wv = threadIdx.x >> 6, lane = threadIdx.x & 63;
    const float* inb = in + (size_t)b * K;
    int n0 = blockIdx.y * 16 + wv * 4;
    for (int q = 0; q < 4; q++) {
        int n = n0 + q;
        const float* wr = W + (size_t)n * K;
        float acc = 0.f;
        for (int c = lane * 4; c < K; c += 256) {
            float4 a  = *(const float4*)(inb + c);
            float4 w4 = *(const float4*)(wr + c);
            acc += a.x * w4.x + a.y * w4.y + a.z * w4.z + a.w * w4.w;
        }
#pragma unroll
        for (int off = 1; off < 64; off <<= 1) acc += __shfl_xor(acc, off, 64);
        if (lane == 0) {
            float x = acc + bias[n];
            out[(size_t)b * N + n] = do_silu ? (x / (1.0f + expf(-x))) : x;
        }
    }
}

// ----------------------------------------------------------------------------
// bf16 split-3 MFMA GEMM: C[orow(r), col] = dot(A[r,:K], W[col,:K]) + bias[col]
// A given as hi/lo bf16 planes [M][K] (GATE: 3 source pairs, 1024 K each);
// W as hi/lo planes [N][K]. Block tile 128x128, wave tile 64x64 (4x4 of
// 16x16x32 MFMA tiles), BK=32, 256 threads.
// Fragment layout (AMD calc / guide m89): a_frag = A[m=lane&15][k=quad*8+j],
// b_frag = W[n=lane&15][k=quad*8+j], D[row=quad*4+reg][col=lane&15].
template<bool GATE, bool RELU, bool KVREMAP>
__global__ __launch_bounds__(256, 2)
void bfgemm_k(const unsigned short* __restrict__ A0h, const unsigned short* __restrict__ A0l,
              const unsigned short* __restrict__ A1h, const unsigned short* __restrict__ A1l,
              const unsigned short* __restrict__ A2h, const unsigned short* __restrict__ A2l,
              const unsigned short* __restrict__ Wh_g, const unsigned short* __restrict__ Wl_g,
              const float* __restrict__ bias, float* __restrict__ C, int K,
              int out_rshift, int out_stride, int out_base, size_t colSegStride)
{
    __shared__ unsigned short Ah[128 * 32];
    __shared__ unsigned short Al[128 * 32];
    __shared__ unsigned short Wh[128 * 32];
    __shared__ unsigned short Wl[128 * 32];
    const int tid = threadIdx.x;
    const int row0 = blockIdx.x * 128;
    const int col0 = blockIdx.y * 128;
    const int wv = tid >> 6;
    const int lane = tid & 63;
    const int wrow = (wv & 1) * 64;
    const int wcol = (wv >> 1) * 64;
    const int l15 = lane & 15, quad = lane >> 4;

    f32x4 acc[4][4];
#pragma unroll
    for (int i = 0; i < 4; i++)
#pragma unroll
        for (int j = 0; j < 4; j++)
            acc[i][j] = (f32x4){0.f, 0.f, 0.f, 0.f};

    // staging indices: thread handles uint4 u0 and u1 per plane
    const int u0 = tid, u1 = tid + 256;
    const int ar0 = u0 >> 2, ak0 = (u0 & 3) * 8;
    const int ar1 = u1 >> 2, ak1 = (u1 & 3) * 8;

    for (int kc = 0; kc < K; kc += 32) {
        const unsigned short* pAh = A0h;
        const unsigned short* pAl = A0l;
        int kk = kc;
        int tembseg = 0;
        if (GATE) {
            int seg = kc >> 10;
            if (seg == 1) { pAh = A1h; pAl = A1l; }
            else if (seg == 2) { pAh = A2h; pAl = A2l; tembseg = 1; }
            kk = kc & 1023;
        }
        const int astr = GATE ? 1024 : K;
        int g0 = row0 + ar0, g1 = row0 + ar1;
        if (GATE && tembseg) { g0 >>= 11; g1 >>= 11; }
        uint4 vah0 = *(const uint4*)&pAh[(size_t)g0 * astr + kk + ak0];
        uint4 vah1 = *(const uint4*)&pAh[(size_t)g1 * astr + kk + ak1];
        uint4 val0 = *(const uint4*)&pAl[(size_t)g0 * astr + kk + ak0];
        uint4 val1 = *(const uint4*)&pAl[(size_t)g1 * astr + kk + ak1];
        uint4 vwh0 = *(const uint4*)&Wh_g[(size_t)(col0 + ar0) * K + kc + ak0];
        uint4 vwh1 = *(const uint4*)&Wh_g[(size_t)(col0 + ar1) * K + kc + ak1];
        uint4 vwl0 = *(const uint4*)&Wl_g[(size_t)(col0 + ar0) * K + kc + ak0];
        uint4 vwl1 = *(const uint4*)&Wl_g[(size_t)(col0 + ar1) * K + kc + ak1];
        __syncthreads();   // previous chunk's frag reads complete
        *(uint4*)&Ah[ar0 * 32 + ak0] = vah0;
        *(uint4*)&Ah[ar1 * 32 + ak1] = vah1;
        *(uint4*)&Al[ar0 * 32 + ak0] = val0;
        *(uint4*)&Al[ar1 * 32 + ak1] = val1;
        *(uint4*)&Wh[ar0 * 32 + ak0] = vwh0;
        *(uint4*)&Wh[ar1 * 32 + ak1] = vwh1;
        *(uint4*)&Wl[ar0 * 32 + ak0] = vwl0;
        *(uint4*)&Wl[ar1 * 32 + ak1] = vwl1;
        __syncthreads();   // staging visible

        short8 a_h[4], a_l[4];
#pragma unroll
        for (int i = 0; i < 4; i++) {
            int r = (wrow + i * 16 + l15) * 32 + quad * 8;
            a_h[i] = *(const short8*)&Ah[r];
            a_l[i] = *(const short8*)&Al[r];
        }
#pragma unroll
        for (int j = 0; j < 4; j++) {
            int c = (wcol + j * 16 + l15) * 32 + quad * 8;
            short8 b_h = *(const short8*)&Wh[c];
            short8 b_l = *(const short8*)&Wl[c];
#pragma unroll
            for (int i = 0; i < 4; i++) {
                acc[i][j] = __builtin_amdgcn_mfma_f32_16x16x32_bf16(a_h[i], b_h, acc[i][j], 0, 0, 0);
                acc[i][j] = __builtin_amdgcn_mfma_f32_16x16x32_bf16(a_h[i], b_l, acc[i][j], 0, 0, 0);
                acc[i][j] = __builtin_amdgcn_mfma_f32_16x16x32_bf16(a_l[i], b_h, acc[i][j], 0, 0, 0);
            }
        }
    }

    // epilogue
#pragma unroll
    for (int i = 0; i < 4; i++) {
#pragma unroll
        for (int j = 0; j < 4; j++) {
            int cc = col0 + wcol + j * 16 + l15;
            float bb = bias[cc];
            float* Cb = C + (size_t)(cc >> 10) * colSegStride + (cc & 1023);
#pragma unroll
            for (int r = 0; r < 4; r++) {
                int rr = row0 + wrow + i * 16 + quad * 4 + r;
                int orow;
                if (KVREMAP) {
                    // rows 0..4095 = outA -> b*2048 + q ; 4096..8191 = outC -> b*2048+1024+q
                    orow = ((rr >> 10) & 3) * 2048 + (rr >> 12) * 1024 + (rr & 1023);
                } else {
                    orow = out_base + (rr >> out_rshift) * out_stride + (rr & ((1 << out_rshift) - 1));
                }
                float v = acc[i][j][r] + bb;
                if (RELU) v = fmaxf(v, 0.f);
                Cb[(size_t)orow * 1024] = v;
            }
        }
    }
}

// ----------------------------------------------------------------------------
// flash-style fp32 attention (R3 version): 64x64 tiles, 4x4 frags, Ks/Ps LDS
// union, register prefetch of next K/V tile. HD=64, S=2048.
__global__ __launch_bounds__(256, 3)
void attn_k(const float* __restrict__ Q, const float* __restrict__ Kb,
            const float* __restrict__ Vb, float* __restrict__ O)
{
    __shared__ float Qs[64][68];    // [d][q], Q pre-scaled by 1/8 (exact pow2)
    __shared__ float KPs[64][68];   // phase 1: K as [d][key]; phase 2: P as [q][key]
    __shared__ float Vs[64][72];    // [key][d]
    const int tid = threadIdx.x;
    const int tx = tid & 15, ty = tid >> 4;
    const int bh = blockIdx.x;            // 0..63
    const int b = bh >> 4, h = bh & 15;
    const int q0 = blockIdx.y * 64;
    const size_t qbase  = ((size_t)(b * 2048 + q0)) * 1024 + h * 64;
    const size_t kvbase = ((size_t)(b * 2048)) * 1024 + h * 64;

    const int m  = tid >> 2;          // 0..63
    const int c4 = (tid & 3) * 4;

#pragma unroll
    for (int tp = 0; tp < 4; tp++) {
        int d4 = tp * 16 + c4;
        float4 v = *(const float4*)(Q + qbase + (size_t)m * 1024 + d4);
        Qs[d4 + 0][m] = v.x * 0.125f; Qs[d4 + 1][m] = v.y * 0.125f;
        Qs[d4 + 2][m] = v.z * 0.125f; Qs[d4 + 3][m] = v.w * 0.125f;
    }
    float4 kr[4], vr[4];
#pragma unroll
    for (int tp = 0; tp < 4; tp++) {
        int d4 = tp * 16 + c4;
        kr[tp] = *(const float4*)(Kb + kvbase + (size_t)m * 1024 + d4);
        vr[tp] = *(const float4*)(Vb + kvbase + (size_t)m * 1024 + d4);
    }
    float o[4][4] = {};
    float mrow[4], lrow[4];
#pragma unroll
    for (int i = 0; i < 4; i++) { mrow[i] = -INFINITY; lrow[i] = 0.f; }
    __syncthreads();

    for (int kt = 0; kt < 32; kt++) {
#pragma unroll
        for (int tp = 0; tp < 4; tp++) {
            int d4 = tp * 16 + c4;
            KPs[d4 + 0][m] = kr[tp].x; KPs[d4 + 1][m] = kr[tp].y;
            KPs[d4 + 2][m] = kr[tp].z; KPs[d4 + 3][m] = kr[tp].w;
            *(float4*)&Vs[m][d4] = vr[tp];
        }
        __syncthreads();
        if (kt + 1 < 32) {
            size_t base2 = kvbase + (size_t)((kt + 1) * 64 + m) * 1024;
#pragma unroll
            for (int tp = 0; tp < 4; tp++) {
                int d4 = tp * 16 + c4;
                kr[tp] = *(const float4*)(Kb + base2 + d4);
                vr[tp] = *(const float4*)(Vb + base2 + d4);
            }
        }
        float s[4][4] = {};
        for (int d = 0; d < 64; d++) {
            float4 qf = *(const float4*)&Qs[d][ty * 4];
            float4 kf = *(const float4*)&KPs[d][tx * 4];
            float qa[4] = {qf.x, qf.y, qf.z, qf.w};
            float ka[4] = {kf.x, kf.y, kf.z, kf.w};
#pragma unroll
            for (int i = 0; i < 4; i++)
#pragma unroll
                for (int j = 0; j < 4; j++)
                    s[i][j] += qa[i] * ka[j];
        }
        __syncthreads();
#pragma unroll
        for (int i = 0; i < 4; i++) {
            float rmax = fmaxf(fmaxf(s[i][0], s[i][1]), fmaxf(s[i][2], s[i][3]));
#pragma unroll
            for (int off = 1; off < 16; off <<= 1)
                rmax = fmaxf(rmax, __shfl_xor(rmax, off, 64));
            float mnew = fmaxf(mrow[i], rmax);
            float corr = expf(mrow[i] - mnew);
            float psum = 0.f;
#pragma unroll
            for (int j = 0; j < 4; j++) { float p = expf(s[i][j] - mnew); s[i][j] = p; psum += p; }
#pragma unroll
            for (int off = 1; off < 16; off <<= 1)
                psum += __shfl_xor(psum, off, 64);
            lrow[i] = lrow[i] * corr + psum;
#pragma unroll
            for (int j = 0; j < 4; j++) o[i][j] *= corr;
            mrow[i] = mnew;
            *(float4*)&KPs[ty * 4 + i][tx * 4] = make_float4(s[i][0], s[i][1], s[i][2], s[i][3]);
        }
        __syncthreads();
#pragma unroll 4
        for (int kq = 0; kq < 16; kq++) {
            float4 pr0 = *(const float4*)&KPs[ty * 4 + 0][kq * 4];
            float4 pr1 = *(const float4*)&KPs[ty * 4 + 1][kq * 4];
            float4 pr2 = *(const float4*)&KPs[ty * 4 + 2][kq * 4];
            float4 pr3 = *(const float4*)&KPs[ty * 4 + 3][kq * 4];
            float4 v0 = *(const float4*)&Vs[kq * 4 + 0][tx * 4];
            float4 v1 = *(const float4*)&Vs[kq * 4 + 1][tx * 4];
            float4 v2 = *(const float4*)&Vs[kq * 4 + 2][tx * 4];
            float4 v3 = *(const float4*)&Vs[kq * 4 + 3][tx * 4];
            float pa[4][4] = {{pr0.x,pr0.y,pr0.z,pr0.w},{pr1.x,pr1.y,pr1.z,pr1.w},
                              {pr2.x,pr2.y,pr2.z,pr2.w},{pr3.x,pr3.y,pr3.z,pr3.w}};
            float va[4][4] = {{v0.x,v0.y,v0.z,v0.w},{v1.x,v1.y,v1.z,v1.w},
                              {v2.x,v2.y,v2.z,v2.w},{v3.x,v3.y,v3.z,v3.w}};
#pragma unroll
            for (int i = 0; i < 4; i++)
#pragma unroll
                for (int l = 0; l < 4; l++)
#pragma unroll
                    for (int j = 0; j < 4; j++)
                        o[i][j] += pa[i][l] * va[l][j];
        }
        __syncthreads();
    }
#pragma unroll
    for (int i = 0; i < 4; i++) {
        float invl = 1.0f / lrow[i];
        int r = q0 + ty * 4 + i;
        float* orow = O + ((size_t)(b * 2048 + r)) * 1024 + h * 64 + tx * 4;
        float4 v;
        v.x = o[i][0] * invl; v.y = o[i][1] * invl;
        v.z = o[i][2] * invl; v.w = o[i][3] * invl;
        *(float4*)orow = v;
    }
}

// ----------------------------------------------------------------------------
// layernorm(X + T) * g + b, emitting bf16 hi/lo planes for the gate GEMM
__global__ __launch_bounds__(256)
void ln_split_k(const float* __restrict__ X, const float* __restrict__ T,
                const float* __restrict__ g, const float* __restrict__ bta,
                unsigned short* __restrict__ chi, unsigned short* __restrict__ clo)
{
    __shared__ float red[8];
    int r = blockIdx.x, tid = threadIdx.x;
    size_t base = (size_t)r * 1024 + tid * 4;
    float4 x  = *(const float4*)(X + base);
    float4 tk = *(const float4*)(T + base);
    x.x += tk.x; x.y += tk.y; x.z += tk.z; x.w += tk.w;
    float s = x.x + x.y + x.z + x.w;
#pragma unroll
    for (int off = 1; off < 64; off <<= 1) s += __shfl_xor(s, off, 64);
    int wv = tid >> 6;
    if ((tid & 63) == 0) red[wv] = s;
    __syncthreads();
    float mu = (red[0] + red[1] + red[2] + red[3]) * (1.0f / 1024.0f);
    float dx0 = x.x - mu, dx1 = x.y - mu, dx2 = x.z - mu, dx3 = x.w - mu;
    float ss = dx0 * dx0 + dx1 * dx1 + dx2 * dx2 + dx3 * dx3;
#pragma unroll
    for (int off = 1; off < 64; off <<= 1) ss += __shfl_xor(ss, off, 64);
    if ((tid & 63) == 0) red[4 + wv] = ss;
    __syncthreads();
    float var = (red[4] + red[5] + red[6] + red[7]) * (1.0f / 1024.0f);
    float inv = 1.0f / sqrtf(var + 1e-5f);
    float4 gg = *(const float4*)(g + tid * 4);
    float4 bb = *(const float4*)(bta + tid * 4);
    float y0 = dx0 * inv * gg.x + bb.x;
    float y1 = dx1 * inv * gg.y + bb.y;
    float y2 = dx2 * inv * gg.z + bb.z;
    float y3 = dx3 * inv * gg.w + bb.w;
    ushort4 h, l;
    h.x = bf_hi(y0); l.x = bf_lo(y0, h.x);
    h.y = bf_hi(y1); l.y = bf_lo(y1, h.y);
    h.z = bf_hi(y2); l.z = bf_lo(y2, h.z);
    h.w = bf_hi(y3); l.w = bf_lo(y3, h.w);
    *(ushort4*)&chi[base] = h;
    *(ushort4*)&clo[base] = l;
}

// ----------------------------------------------------------------------------
// logits[r][e] = dot(hidden[r], W2[e]) + b2[e] + eb[e]; one wave per row (fp32)
__global__ __launch_bounds__(256)
void logits_k(const float* __restrict__ Hd, const float* __restrict__ W2,
              const float* __restrict__ b2, const float* __restrict__ eb,
              float* __restrict__ Lg)
{
    int gw = (blockIdx.x * 256 + threadIdx.x) >> 6;  // row 0..8191
    int lane = threadIdx.x & 63;
    const float* h = Hd + (size_t)gw * 1024;
    float4 hv[4];
#pragma unroll
    for (int j = 0; j < 4; j++) hv[j] = *(const float4*)(h + j * 256 + lane * 4);
    float res[8];
#pragma unroll
    for (int e = 0; e < 8; e++) {
        const float* w = W2 + (size_t)e * 1024;
        float acc = 0.f;
#pragma unroll
        for (int j = 0; j < 4; j++) {
            float4 w4 = *(const float4*)(w + j * 256 + lane * 4);
            acc += hv[j].x * w4.x + hv[j].y * w4.y + hv[j].z * w4.z + hv[j].w * w4.w;
        }
#pragma unroll
        for (int off = 1; off < 64; off <<= 1) acc += __shfl_xor(acc, off, 64);
        res[e] = acc;
    }
    if (lane < 8) {
        float v = res[0];
#pragma unroll
        for (int e = 1; e < 8; e++) v = (lane == e) ? res[e] : v;
        Lg[(size_t)gw * 8 + lane] = v + b2[lane] + eb[lane];
    }
}

// ----------------------------------------------------------------------------
// full routing epilogue: one thread per token
__global__ __launch_bounds__(256)
void router_k(const float* __restrict__ Lg, const int* __restrict__ t,
              float* __restrict__ outp, double* __restrict__ loadAcc)
{
    __shared__ double wred[4][8];
    int tid = threadIdx.x;
    int r = blockIdx.x * 256 + tid;   // 0..8191
    int b = r >> 11;
    float tn  = (float)t[b] / 1000.0f;
    float tau = 0.5f + 1.5f * tn;
    float p[8];
    float mx = -INFINITY;
#pragma unroll
    for (int e = 0; e < 8; e++) { p[e] = Lg[(size_t)r * 8 + e] / tau; mx = fmaxf(mx, p[e]); }
    float sum = 0.f;
#pragma unroll
    for (int e = 0; e < 8; e++) { p[e] = expf(p[e] - mx); sum += p[e]; }
#pragma unroll
    for (int e = 0; e < 8; e++) p[e] = p[e] / sum;
#pragma unroll
    for (int e = 0; e < 8; e++) p[e] = 0.85f * p[e] + 0.01875f;   // (1-ALPHA)p + ALPHA/E
    float w = 0.1f + 0.1f * tn;
    float shared_p = fmaxf(p[0], w);
    float osum = 0.f;
#pragma unroll
    for (int e = 1; e < 8; e++) osum += p[e];
    float denom_o = fmaxf(osum, 1e-8f);
    float one_m = 1.0f - shared_p;
    p[0] = shared_p;
#pragma unroll
    for (int e = 1; e < 8; e++) p[e] = (p[e] / denom_o) * one_m;  // match np op order
    int i0 = 0; float v0 = p[0];
#pragma unroll
    for (int e = 1; e < 8; e++) if (p[e] > v0) { v0 = p[e]; i0 = e; }
    int i1 = -1; float v1 = -INFINITY;
#pragma unroll
    for (int e = 0; e < 8; e++) if (e != i0 && p[e] > v1) { v1 = p[e]; i1 = e; }
    float cap = 0.5f + 0.1f * tn;
    float dsp[8], capped[8], hr[8];
    float exsum = 0.f, hsum = 0.f;
#pragma unroll
    for (int e = 0; e < 8; e++) {
        float d = ((e == i0) ? v0 : 0.f) + ((e == i1) ? v1 : 0.f);
        float ex = fmaxf(d - cap, 0.f);
        float c = d - ex;
        float h = fmaxf(cap - c, 0.f);
        capped[e] = c; hr[e] = h;
        exsum += ex; hsum += h;
    }
    float hden = fmaxf(hsum, 1e-8f);
    float dsum = 0.f;
#pragma unroll
    for (int e = 0; e < 8; e++) {
        float d = capped[e] + exsum * (hr[e] / hden);
        dsp[e] = d; dsum += d;
    }
    float cden = dsum + 1e-8f;
#pragma unroll
    for (int e = 0; e < 8; e++) {
        outp[(size_t)r * 8 + e] = dsp[e];
        outp[65536 + (size_t)r * 8 + e] = dsp[e] / cden;
    }
    int lane = tid & 63, wv = tid >> 6;
#pragma unroll
    for (int e = 0; e < 8; e++) {
        double s = (double)dsp[e];
#pragma unroll
        for (int off = 1; off < 64; off <<= 1) s += __shfl_xor(s, off, 64);
        if (lane == 0) wred[wv][e] = s;
    }
    __syncthreads();
    if (tid < 8) {
        double s = wred[0][tid] + wred[1][tid] + wred[2][tid] + wred[3][tid];
        atomicAdd(&loadAcc[tid], s);
    }
}

// ----------------------------------------------------------------------------
__global__ void penalty_k(const double* __restrict__ loadAcc, float* __restrict__ outp) {
    if (threadIdx.x == 0) {
        const float thr = (float)(2048.0 / 7.0 * 1.5);  // fair * 1.5
        float pen = 0.f;
#pragma unroll
        for (int e = 1; e < 8; e++) {
            float load = (float)(loadAcc[e] / 4.0);     // mean over B
            float x = fmaxf(load - thr, 0.f);
            pen += x * x;
        }
        outp[131072] = 0.01f * pen;
    }
}

// ----------------------------------------------------------------------------
extern "C" void kernel_launch(void* const* d_in, const int* in_sizes, int n_in,
                              void* d_out, int out_size, void* d_ws, size_t ws_size,
                              hipStream_t stream)
{
    const float* tokens = (const float*)d_in[0];
    const float* outA   = (const float*)d_in[1];
    const float* outC   = (const float*)d_in[2];
    const int*   tt     = (const int*)  d_in[3];
    const float* in_w   = (const float*)d_in[4];
    const float* in_b   = (const float*)d_in[5];
    const float* op_w   = (const float*)d_in[6];
    const float* op_b   = (const float*)d_in[7];
    const float* lng    = (const float*)d_in[8];
    const float* lnb    = (const float*)d_in[9];
    const float* te_w1  = (const float*)d_in[10];
    const float* te_b1  = (const float*)d_in[11];
    const float* te_w2  = (const float*)d_in[12];
    const float* te_b2  = (const float*)d_in[13];
    const float* g_w1   = (const float*)d_in[14];
    const float* g_b1   = (const float*)d_in[15];
    const float* g_w2   = (const float*)d_in[16];
    const float* g_b2   = (const float*)d_in[17];
    const float* e_bias = (const float*)d_in[18];
    float* out = (float*)d_out;

    float* ws = (float*)d_ws;
    const size_t NM = (size_t)8192 * 1024;
    float* bq   = ws;            // q proj -> later gate hidden
    float* bk   = ws + NM;       // k proj -> (stays fp32 K for attn)
    float* bv   = ws + 2 * NM;   // v proj -> later out_proj raw
    float* bo   = ws + 3 * NM;   // attention output
    float* temb    = ws + 4 * NM;        // 4x1024 fp32
    float* embb    = temb + 4096;
    float* hte     = embb + 4096;        // 4x2048
    float* logitsb = hte + 8192;         // 8192x8
    double* loads  = (double*)(logitsb + 65536);   // 8 doubles

    // bf16 plane region (ushort)
    unsigned short* ub = (unsigned short*)(logitsb + 65536 + 16);
    const size_t AN = NM;                 // 8192*1024 elements per plane
    unsigned short* A1h = ub;             // tokens split (alive whole launch)
    unsigned short* A1l = A1h + AN;
    unsigned short* A2h = A1l + AN;       // outA|outC -> bo -> ctx_B (sequenced)
    unsigned short* A2l = A2h + AN;
    unsigned short* Wsh = A2l + AN;       // weight split buffer (3M elems max)
    unsigned short* Wsl = Wsh + (size_t)3 * 1024 * 1024;
    unsigned short* Tbh = Wsl + (size_t)3 * 1024 * 1024;   // temb split, 4096
    unsigned short* Tbl = Tbh + 4096;

    zero_k<<<1, 64, 0, stream>>>(loads);
    emb_k<<<4, 512, 0, stream>>>(tt, embb);
    te_fc_k<<<dim3(4, 128), 256, 0, stream>>>(embb, te_w1, te_b1, hte, 1024, 2048, 1);
    te_fc_k<<<dim3(4, 64),  256, 0, stream>>>(hte,  te_w2, te_b2, temb, 2048, 1024, 0);

    // splits for q/kv
    split_k<<<8192, 256, 0, stream>>>(tokens, A1h, A1l, 8192 * 1024 / 4);
    split_k<<<3072, 256, 0, stream>>>(in_w, Wsh, Wsl, 3 * 1024 * 1024 / 4);

    // q = tokens @ wq.T + bq   (M=8192, N=1024, K=1024)
    bfgemm_k<false, false, false><<<dim3(64, 8), 256, 0, stream>>>(
        A1h, A1l, nullptr, nullptr, nullptr, nullptr,
        Wsh, Wsl, in_b, bq, 1024, 13, 0, 0, 0);

    // k & v: A = [outA ; outC] split rows 0..8191, W = in_w rows 1024..3071,
    // cols 0..1023 -> bk, 1024..2047 -> bv, KV row remap
    split_k<<<4096, 256, 0, stream>>>(outA, A2h, A2l, 4096 * 1024 / 4);
    split_k<<<4096, 256, 0, stream>>>(outC, A2h + (size_t)4096 * 1024,
                                      A2l + (size_t)4096 * 1024, 4096 * 1024 / 4);
    bfgemm_k<false, false, true><<<dim3(64, 16), 256, 0, stream>>>(
        A2h, A2l, nullptr, nullptr, nullptr, nullptr,
        Wsh + (size_t)1024 * 1024, Wsl + (size_t)1024 * 1024,
        in_b + 1024, bk, 1024, 0, 0, 0, NM);

    attn_k<<<dim3(64, 32), 256, 0, stream>>>(bq, bk, bv, bo);

    // out_proj: split bo and op_w, GEMM -> bv (V dead after attn)
    split_k<<<8192, 256, 0, stream>>>(bo, A2h, A2l, 8192 * 1024 / 4);
    split_k<<<1024, 256, 0, stream>>>(op_w, Wsh, Wsl, 1024 * 1024 / 4);
    bfgemm_k<false, false, false><<<dim3(64, 8), 256, 0, stream>>>(
        A2h, A2l, nullptr, nullptr, nullptr, nullptr,
        Wsh, Wsl, op_b, bv, 1024, 13, 0, 0, 0);

    // ctx_B = LN(out_proj + tokens) -> split planes directly into A2
    ln_split_k<<<8192, 256, 0, stream>>>(bv, tokens, lng, lnb, A2h, A2l);

    // gate: [tokens | ctx_B | t_emb] @ gate_w1.T + b1, relu -> bq (fp32)
    split_k<<<4, 256, 0, stream>>>(temb, Tbh, Tbl, 4096 / 4);
    split_k<<<3072, 256, 0, stream>>>(g_w1, Wsh, Wsl, 3072 * 1024 / 4);
    bfgemm_k<true, true, false><<<dim3(64, 8), 256, 0, stream>>>(
        A1h, A1l, A2h, A2l, Tbh, Tbl,
        Wsh, Wsl, g_b1, bq, 3072, 13, 0, 0, 0);

    logits_k<<<2048, 256, 0, stream>>>(bq, g_w2, g_b2, e_bias, logitsb);
    router_k<<<32, 256, 0, stream>>>(logitsb, tt, out, loads);
    penalty_k<<<1, 64, 0, stream>>>(loads, out);
}

// Round 6
// 823.072 us; speedup vs baseline: 3.5396x; 1.9872x over previous
//
#include <hip/hip_runtime.h>
#include <math.h>

// Problem constants
//   B=4, NB=2048, NA=NC=1024, D=1024, E=8, H=16, HD=64, TOP_K=2
// R3 lesson: NO lambdas capturing register arrays in hot kernels (scratch spills).
// R4 lesson: transpose-store staging maps must be checked for bank collapse.
// R5: GEMMs on bf16 split-3 MFMA (hi*hi+hi*lo+lo*hi), err ~2^-16 — verified safe.
// R6: attention on split-3 MFMA too. No-max softmax (scores bounded ~2.4, exp safe,
//     result identical after the final division). Q/K/V planes produced by GEMM
//     epilogues (V transposed via operand swap); attn writes ctx planes onto the
//     Q planes (block-disjoint). P round-trips LDS as packed (hi<<16|lo) uint.

typedef __attribute__((ext_vector_type(8))) short short8;
typedef __attribute__((ext_vector_type(4))) float f32x4;
typedef unsigned short u16;
typedef unsigned int u32;

// ----------------------------------------------------------------------------
__global__ void zero_k(double* p) {
    if (threadIdx.x < 8) p[threadIdx.x] = 0.0;
}

// ----------------------------------------------------------------------------
// fp32 -> bf16 hi/lo split helpers (RNE)
__device__ inline u16 bf_hi(float x) {
    u32 u = __float_as_uint(x);
    u += 0x7FFFu + ((u >> 16) & 1u);
    return (u16)(u >> 16);
}
__device__ inline u16 bf_lo(float x, u16 h) {
    float hf = __uint_as_float(((u32)h) << 16);
    return bf_hi(x - hf);
}
__device__ inline u32 pack_bf(float x) {
    u32 u = __float_as_uint(x);
    u32 hi = (u + (0x7FFFu + ((u >> 16) & 1u))) >> 16;
    float hf = __uint_as_float(hi << 16);
    float d = x - hf;
    u32 u2 = __float_as_uint(d);
    u32 lo = (u2 + (0x7FFFu + ((u2 >> 16) & 1u))) >> 16;
    return (hi << 16) | lo;
}

__global__ __launch_bounds__(256)
void split_k(const float* __restrict__ in, u16* __restrict__ hi,
             u16* __restrict__ lo, int n4) {
    int i = blockIdx.x * 256 + threadIdx.x;
    if (i >= n4) return;
    float4 x = ((const float4*)in)[i];
    ushort4 h, l;
    h.x = bf_hi(x.x); l.x = bf_lo(x.x, h.x);
    h.y = bf_hi(x.y); l.y = bf_lo(x.y, h.y);
    h.z = bf_hi(x.z); l.z = bf_lo(x.z, h.z);
    h.w = bf_hi(x.w); l.w = bf_lo(x.w, h.w);
    ((ushort4*)hi)[i] = h;
    ((ushort4*)lo)[i] = l;
}

// ----------------------------------------------------------------------------
__global__ void emb_k(const int* __restrict__ t, float* __restrict__ emb) {
    int b = blockIdx.x;
    int j = threadIdx.x; // 0..511
    float x1 = (float)(-9.210340371976184) * (float)j;
    float x2 = x1 / 511.0f;
    float freq = (float)exp((double)x2);
    float tf = (float)t[b];
    float arg = tf * freq;
    emb[b * 1024 + j]       = (float)sin((double)arg);
    emb[b * 1024 + 512 + j] = (float)cos((double)arg);
}

// ----------------------------------------------------------------------------
__global__ void te_fc_k(const float* __restrict__ in, const float* __restrict__ W,
                        const float* __restrict__ bias, float* __restrict__ out,
                        int K, int N, int do_silu) {
    int b = blockIdx.x;
    int wv = threadIdx.x >> 6, lane = threadIdx.x & 63;
    const float* inb = in + (size_t)b * K;
    int n0 = blockIdx.y * 16 + wv * 4;
    for (int q = 0; q < 4; q++) {
        int n = n0 + q;
        const float* wr = W + (size_t)n * K;
        float acc = 0.f;
        for (int c = lane * 4; c < K; c += 256) {
            float4 a  = *(const float4*)(inb + c);
            float4 w4 = *(const float4*)(wr + c);
            acc += a.x * w4.x + a.y * w4.y + a.z * w4.z + a.w * w4.w;
        }
#pragma unroll
        for (int off = 1; off < 64; off <<= 1) acc += __shfl_xor(acc, off, 64);
        if (lane == 0) {
            float x = acc + bias[n];
            out[(size_t)b * N + n] = do_silu ? (x / (1.0f + expf(-x))) : x;
        }
    }
}

// ----------------------------------------------------------------------------
// bf16 split-3 MFMA GEMM. C[rr,cc] = dot(A[rr,:K], W[cc,:K]) + bias.
// OMODE: 0 = fp32 out (identity rows), 1 = bf16 hi/lo planes (identity),
//        2 = bf16 planes with KV row remap (K proj), 3 = transposed V^T planes
//        (rows = v-col, cols = act rows; bias indexed by ROW).
template<bool GATE, bool RELU, int OMODE>
__global__ __launch_bounds__(256, 2)
void bfgemm_k(const u16* __restrict__ A0h, const u16* __restrict__ A0l,
              const u16* __restrict__ A1h, const u16* __restrict__ A1l,
              const u16* __restrict__ A2h, const u16* __restrict__ A2l,
              const u16* __restrict__ Wh_g, const u16* __restrict__ Wl_g,
              const float* __restrict__ bias, float* __restrict__ C,
              u16* __restrict__ Chi, u16* __restrict__ Clo, int K)
{
    __shared__ u16 Ah[128 * 32];
    __shared__ u16 Al[128 * 32];
    __shared__ u16 Wh[128 * 32];
    __shared__ u16 Wl[128 * 32];
    const int tid = threadIdx.x;
    const int row0 = blockIdx.x * 128;
    const int col0 = blockIdx.y * 128;
    const int wv = tid >> 6;
    const int lane = tid & 63;
    const int wrow = (wv & 1) * 64;
    const int wcol = (wv >> 1) * 64;
    const int l15 = lane & 15, quad = lane >> 4;

    f32x4 acc[4][4];
#pragma unroll
    for (int i = 0; i < 4; i++)
#pragma unroll
        for (int j = 0; j < 4; j++)
            acc[i][j] = (f32x4){0.f, 0.f, 0.f, 0.f};

    const int ar0 = tid >> 2, ak0 = (tid & 3) * 8;
    const int ar1 = (tid + 256) >> 2, ak1 = ((tid + 256) & 3) * 8;

    for (int kc = 0; kc < K; kc += 32) {
        const u16* pAh = A0h;
        const u16* pAl = A0l;
        int kk = kc;
        int tembseg = 0;
        if (GATE) {
            int seg = kc >> 10;
            if (seg == 1) { pAh = A1h; pAl = A1l; }
            else if (seg == 2) { pAh = A2h; pAl = A2l; tembseg = 1; }
            kk = kc & 1023;
        }
        const int astr = GATE ? 1024 : K;
        int g0 = row0 + ar0, g1 = row0 + ar1;
        if (GATE && tembseg) { g0 >>= 11; g1 >>= 11; }
        uint4 vah0 = *(const uint4*)&pAh[(size_t)g0 * astr + kk + ak0];
        uint4 vah1 = *(const uint4*)&pAh[(size_t)g1 * astr + kk + ak1];
        uint4 val0 = *(const uint4*)&pAl[(size_t)g0 * astr + kk + ak0];
        uint4 val1 = *(const uint4*)&pAl[(size_t)g1 * astr + kk + ak1];
        uint4 vwh0 = *(const uint4*)&Wh_g[(size_t)(col0 + ar0) * K + kc + ak0];
        uint4 vwh1 = *(const uint4*)&Wh_g[(size_t)(col0 + ar1) * K + kc + ak1];
        uint4 vwl0 = *(const uint4*)&Wl_g[(size_t)(col0 + ar0) * K + kc + ak0];
        uint4 vwl1 = *(const uint4*)&Wl_g[(size_t)(col0 + ar1) * K + kc + ak1];
        __syncthreads();
        *(uint4*)&Ah[ar0 * 32 + ak0] = vah0;
        *(uint4*)&Ah[ar1 * 32 + ak1] = vah1;
        *(uint4*)&Al[ar0 * 32 + ak0] = val0;
        *(uint4*)&Al[ar1 * 32 + ak1] = val1;
        *(uint4*)&Wh[ar0 * 32 + ak0] = vwh0;
        *(uint4*)&Wh[ar1 * 32 + ak1] = vwh1;
        *(uint4*)&Wl[ar0 * 32 + ak0] = vwl0;
        *(uint4*)&Wl[ar1 * 32 + ak1] = vwl1;
        __syncthreads();

        short8 a_h[4], a_l[4];
#pragma unroll
        for (int i = 0; i < 4; i++) {
            int r = (wrow + i * 16 + l15) * 32 + quad * 8;
            a_h[i] = *(const short8*)&Ah[r];
            a_l[i] = *(const short8*)&Al[r];
        }
#pragma unroll
        for (int j = 0; j < 4; j++) {
            int c = (wcol + j * 16 + l15) * 32 + quad * 8;
            short8 b_h = *(const short8*)&Wh[c];
            short8 b_l = *(const short8*)&Wl[c];
#pragma unroll
            for (int i = 0; i < 4; i++) {
                acc[i][j] = __builtin_amdgcn_mfma_f32_16x16x32_bf16(a_h[i], b_h, acc[i][j], 0, 0, 0);
                acc[i][j] = __builtin_amdgcn_mfma_f32_16x16x32_bf16(a_h[i], b_l, acc[i][j], 0, 0, 0);
                acc[i][j] = __builtin_amdgcn_mfma_f32_16x16x32_bf16(a_l[i], b_h, acc[i][j], 0, 0, 0);
            }
        }
    }

#pragma unroll
    for (int i = 0; i < 4; i++) {
#pragma unroll
        for (int j = 0; j < 4; j++) {
            int cc = col0 + wcol + j * 16 + l15;
#pragma unroll
            for (int r = 0; r < 4; r++) {
                int rr = row0 + wrow + i * 16 + quad * 4 + r;
                float v = acc[i][j][r] + ((OMODE == 3) ? bias[rr] : bias[cc]);
                if (RELU) v = fmaxf(v, 0.f);
                if (OMODE == 0) {
                    C[(size_t)rr * 1024 + cc] = v;
                } else if (OMODE == 1) {
                    u32 pk = pack_bf(v);
                    size_t a = (size_t)rr * 1024 + cc;
                    Chi[a] = (u16)(pk >> 16); Clo[a] = (u16)pk;
                } else if (OMODE == 2) {
                    int orow = ((rr >> 10) & 3) * 2048 + (rr >> 12) * 1024 + (rr & 1023);
                    u32 pk = pack_bf(v);
                    size_t a = (size_t)orow * 1024 + cc;
                    Chi[a] = (u16)(pk >> 16); Clo[a] = (u16)pk;
                } else {
                    int bb2 = (cc >> 10) & 3;
                    int key = (cc >> 12) * 1024 + (cc & 1023);
                    u32 pk = pack_bf(v);
                    size_t a = ((size_t)(bb2 * 1024 + rr)) * 2048 + key;
                    Chi[a] = (u16)(pk >> 16); Clo[a] = (u16)pk;
                }
            }
        }
    }
}

// ----------------------------------------------------------------------------
// MFMA flash attention, split-3 bf16, no-max softmax.
// Block: 512 thr (8 waves), q-tile 256 (32 q/wave), k-tile 64, 32 k-steps.
// LDS: P region [256][76] u32 (K tiles alias its front); V tiles [2][64*72] u16.
__global__ __launch_bounds__(512, 1)
void attn_k(const u16* Qh, const u16* Ql,
            const u16* __restrict__ Kh, const u16* __restrict__ Kl,
            const u16* __restrict__ Vh, const u16* __restrict__ Vl,
            u16* Oh, u16* Ol)
{
    __shared__ u32 Pu[256 * 76];          // 77824 B
    __shared__ u16 Vsm[2][64 * 72];       // 18432 B
    u16* Ksh = (u16*)Pu;
    u16* Ksl = Ksh + 64 * 72;

    const int tid = threadIdx.x;
    const int w = tid >> 6, lane = tid & 63;
    const int l15 = lane & 15, quad = lane >> 4;
    const int bh = blockIdx.x, b = bh >> 4, h = bh & 15;
    const int qw = blockIdx.y * 256 + w * 32;          // local q base of this wave
    const int qrow0 = b * 2048 + qw;                    // global Q plane row base

    // Q A-fragments in registers
    short8 qh_f[2][2], ql_f[2][2];
#pragma unroll
    for (int i = 0; i < 2; i++)
#pragma unroll
        for (int kc = 0; kc < 2; kc++) {
            size_t a = (size_t)(qrow0 + i * 16 + l15) * 1024 + h * 64 + kc * 32 + quad * 8;
            qh_f[i][kc] = *(const short8*)&Qh[a];
            ql_f[i][kc] = *(const short8*)&Ql[a];
        }

    // staging: one ushort8 per plane per thread for K and V
    const int skey = tid >> 3, sdb = (tid & 7) * 8;
    const int lds_k = skey * 72 + sdb;
    const size_t g_k = ((size_t)(b * 2048) + skey) * 1024 + h * 64 + sdb;
    const int vd = tid >> 3, vkb = (tid & 7) * 8;
    const int lds_v = vd * 72 + vkb;
    const size_t g_v = ((size_t)((b * 16 + h) * 64 + vd)) * 2048 + vkb;

    uint4 pk_h = *(const uint4*)&Kh[g_k];
    uint4 pk_l = *(const uint4*)&Kl[g_k];
    uint4 pv_h = *(const uint4*)&Vh[g_v];
    uint4 pv_l = *(const uint4*)&Vl[g_v];

    f32x4 o[2][4];
#pragma unroll
    for (int i = 0; i < 2; i++)
#pragma unroll
        for (int j = 0; j < 4; j++) o[i][j] = (f32x4){0.f, 0.f, 0.f, 0.f};
    float lsum[2][4] = {};

    for (int kt = 0; kt < 32; kt++) {
        __syncthreads();               // prev PV (P + V reads) complete
        *(uint4*)&Ksh[lds_k] = pk_h;
        *(uint4*)&Ksl[lds_k] = pk_l;
        *(uint4*)&Vsm[0][lds_v] = pv_h;
        *(uint4*)&Vsm[1][lds_v] = pv_l;
        __syncthreads();               // staging visible
        if (kt < 31) {
            size_t gk2 = g_k + (size_t)(kt + 1) * 65536;
            size_t gv2 = g_v + (size_t)(kt + 1) * 64;
            pk_h = *(const uint4*)&Kh[gk2];
            pk_l = *(const uint4*)&Kl[gk2];
            pv_h = *(const uint4*)&Vh[gv2];
            pv_l = *(const uint4*)&Vl[gv2];
        }
        // QK^T
        f32x4 s[2][4];
#pragma unroll
        for (int i = 0; i < 2; i++)
#pragma unroll
            for (int j = 0; j < 4; j++) s[i][j] = (f32x4){0.f, 0.f, 0.f, 0.f};
#pragma unroll
        for (int j = 0; j < 4; j++) {
            int ka = (j * 16 + l15) * 72 + quad * 8;
            short8 kh0 = *(const short8*)&Ksh[ka];
            short8 kh1 = *(const short8*)&Ksh[ka + 32];
            short8 kl0 = *(const short8*)&Ksl[ka];
            short8 kl1 = *(const short8*)&Ksl[ka + 32];
#pragma unroll
            for (int i = 0; i < 2; i++) {
                s[i][j] = __builtin_amdgcn_mfma_f32_16x16x32_bf16(qh_f[i][0], kh0, s[i][j], 0, 0, 0);
                s[i][j] = __builtin_amdgcn_mfma_f32_16x16x32_bf16(qh_f[i][0], kl0, s[i][j], 0, 0, 0);
                s[i][j] = __builtin_amdgcn_mfma_f32_16x16x32_bf16(ql_f[i][0], kh0, s[i][j], 0, 0, 0);
                s[i][j] = __builtin_amdgcn_mfma_f32_16x16x32_bf16(qh_f[i][1], kh1, s[i][j], 0, 0, 0);
                s[i][j] = __builtin_amdgcn_mfma_f32_16x16x32_bf16(qh_f[i][1], kl1, s[i][j], 0, 0, 0);
                s[i][j] = __builtin_amdgcn_mfma_f32_16x16x32_bf16(ql_f[i][1], kh1, s[i][j], 0, 0, 0);
            }
        }
        __syncthreads();               // all K reads done -> K region becomes P
        // exp (no max-sub: |s/8| <= ~3) + pack hi/lo + store P + lsum
#pragma unroll
        for (int i = 0; i < 2; i++)
#pragma unroll
            for (int j = 0; j < 4; j++)
#pragma unroll
                for (int r = 0; r < 4; r++) {
                    float p = __expf(s[i][j][r] * 0.125f);
                    lsum[i][r] += p;
                    Pu[(w * 32 + i * 16 + quad * 4 + r) * 76 + j * 16 + l15] = pack_bf(p);
                }
        // each wave reads only its own P rows -> in-wave DS ordering suffices
#pragma unroll
        for (int kc = 0; kc < 2; kc++) {
            short8 ph[2], pl[2];
#pragma unroll
            for (int i = 0; i < 2; i++) {
                const uint4* pp = (const uint4*)&Pu[(w * 32 + i * 16 + l15) * 76 + kc * 32 + quad * 8];
                uint4 u0 = pp[0], u1 = pp[1];
                ph[i][0] = (short)(u0.x >> 16); pl[i][0] = (short)(u0.x & 0xffff);
                ph[i][1] = (short)(u0.y >> 16); pl[i][1] = (short)(u0.y & 0xffff);
                ph[i][2] = (short)(u0.z >> 16); pl[i][2] = (short)(u0.z & 0xffff);
                ph[i][3] = (short)(u0.w >> 16); pl[i][3] = (short)(u0.w & 0xffff);
                ph[i][4] = (short)(u1.x >> 16); pl[i][4] = (short)(u1.x & 0xffff);
                ph[i][5] = (short)(u1.y >> 16); pl[i][5] = (short)(u1.y & 0xffff);
                ph[i][6] = (short)(u1.z >> 16); pl[i][6] = (short)(u1.z & 0xffff);
                ph[i][7] = (short)(u1.w >> 16); pl[i][7] = (short)(u1.w & 0xffff);
            }
#pragma unroll
            for (int jd = 0; jd < 4; jd++) {
                int va = (jd * 16 + l15) * 72 + kc * 32 + quad * 8;
                short8 vvh = *(const short8*)&Vsm[0][va];
                short8 vvl = *(const short8*)&Vsm[1][va];
#pragma unroll
                for (int i = 0; i < 2; i++) {
                    o[i][jd] = __builtin_amdgcn_mfma_f32_16x16x32_bf16(ph[i], vvh, o[i][jd], 0, 0, 0);
                    o[i][jd] = __builtin_amdgcn_mfma_f32_16x16x32_bf16(ph[i], vvl, o[i][jd], 0, 0, 0);
                    o[i][jd] = __builtin_amdgcn_mfma_f32_16x16x32_bf16(pl[i], vvh, o[i][jd], 0, 0, 0);
                }
            }
        }
    }
    // reduce lsum across the 16 key-lanes (xor 1,2,4,8 stay within quad rows)
#pragma unroll
    for (int i = 0; i < 2; i++)
#pragma unroll
        for (int r = 0; r < 4; r++) {
            float s2 = lsum[i][r];
            s2 += __shfl_xor(s2, 1, 64);
            s2 += __shfl_xor(s2, 2, 64);
            s2 += __shfl_xor(s2, 4, 64);
            s2 += __shfl_xor(s2, 8, 64);
            lsum[i][r] = s2;
        }
    // epilogue: ctx = o / l -> bf16 hi/lo planes (overwrites this block's Q region)
#pragma unroll
    for (int i = 0; i < 2; i++)
#pragma unroll
        for (int jd = 0; jd < 4; jd++)
#pragma unroll
            for (int r = 0; r < 4; r++) {
                float v = o[i][jd][r] / lsum[i][r];
                u32 pk = pack_bf(v);
                size_t a = (size_t)(qrow0 + i * 16 + quad * 4 + r) * 1024 + h * 64 + jd * 16 + l15;
                Oh[a] = (u16)(pk >> 16);
                Ol[a] = (u16)pk;
            }
}

// ----------------------------------------------------------------------------
// layernorm(X + T) * g + b, emitting bf16 hi/lo planes for the gate GEMM
__global__ __launch_bounds__(256)
void ln_split_k(const float* __restrict__ X, const float* __restrict__ T,
                const float* __restrict__ g, const float* __restrict__ bta,
                u16* __restrict__ chi, u16* __restrict__ clo)
{
    __shared__ float red[8];
    int r = blockIdx.x, tid = threadIdx.x;
    size_t base = (size_t)r * 1024 + tid * 4;
    float4 x  = *(const float4*)(X + base);
    float4 tk = *(const float4*)(T + base);
    x.x += tk.x; x.y += tk.y; x.z += tk.z; x.w += tk.w;
    float s = x.x + x.y + x.z + x.w;
#pragma unroll
    for (int off = 1; off < 64; off <<= 1) s += __shfl_xor(s, off, 64);
    int wv = tid >> 6;
    if ((tid & 63) == 0) red[wv] = s;
    __syncthreads();
    float mu = (red[0] + red[1] + red[2] + red[3]) * (1.0f / 1024.0f);
    float dx0 = x.x - mu, dx1 = x.y - mu, dx2 = x.z - mu, dx3 = x.w - mu;
    float ss = dx0 * dx0 + dx1 * dx1 + dx2 * dx2 + dx3 * dx3;
#pragma unroll
    for (int off = 1; off < 64; off <<= 1) ss += __shfl_xor(ss, off, 64);
    if ((tid & 63) == 0) red[4 + wv] = ss;
    __syncthreads();
    float var = (red[4] + red[5] + red[6] + red[7]) * (1.0f / 1024.0f);
    float inv = 1.0f / sqrtf(var + 1e-5f);
    float4 gg = *(const float4*)(g + tid * 4);
    float4 bb = *(const float4*)(bta + tid * 4);
    float y0 = dx0 * inv * gg.x + bb.x;
    float y1 = dx1 * inv * gg.y + bb.y;
    float y2 = dx2 * inv * gg.z + bb.z;
    float y3 = dx3 * inv * gg.w + bb.w;
    ushort4 h, l;
    h.x = bf_hi(y0); l.x = bf_lo(y0, h.x);
    h.y = bf_hi(y1); l.y = bf_lo(y1, h.y);
    h.z = bf_hi(y2); l.z = bf_lo(y2, h.z);
    h.w = bf_hi(y3); l.w = bf_lo(y3, h.w);
    *(ushort4*)&chi[base] = h;
    *(ushort4*)&clo[base] = l;
}

// ----------------------------------------------------------------------------
__global__ __launch_bounds__(256)
void logits_k(const float* __restrict__ Hd, const float* __restrict__ W2,
              const float* __restrict__ b2, const float* __restrict__ eb,
              float* __restrict__ Lg)
{
    int gw = (blockIdx.x * 256 + threadIdx.x) >> 6;  // row 0..8191
    int lane = threadIdx.x & 63;
    const float* h = Hd + (size_t)gw * 1024;
    float4 hv[4];
#pragma unroll
    for (int j = 0; j < 4; j++) hv[j] = *(const float4*)(h + j * 256 + lane * 4);
    float res[8];
#pragma unroll
    for (int e = 0; e < 8; e++) {
        const float* w = W2 + (size_t)e * 1024;
        float acc = 0.f;
#pragma unroll
        for (int j = 0; j < 4; j++) {
            float4 w4 = *(const float4*)(w + j * 256 + lane * 4);
            acc += hv[j].x * w4.x + hv[j].y * w4.y + hv[j].z * w4.z + hv[j].w * w4.w;
        }
#pragma unroll
        for (int off = 1; off < 64; off <<= 1) acc += __shfl_xor(acc, off, 64);
        res[e] = acc;
    }
    if (lane < 8) {
        float v = res[0];
#pragma unroll
        for (int e = 1; e < 8; e++) v = (lane == e) ? res[e] : v;
        Lg[(size_t)gw * 8 + lane] = v + b2[lane] + eb[lane];
    }
}

// ----------------------------------------------------------------------------
__global__ __launch_bounds__(256)
void router_k(const float* __restrict__ Lg, const int* __restrict__ t,
              float* __restrict__ outp, double* __restrict__ loadAcc)
{
    __shared__ double wred[4][8];
    int tid = threadIdx.x;
    int r = blockIdx.x * 256 + tid;   // 0..8191
    int b = r >> 11;
    float tn  = (float)t[b] / 1000.0f;
    float tau = 0.5f + 1.5f * tn;
    float p[8];
    float mx = -INFINITY;
#pragma unroll
    for (int e = 0; e < 8; e++) { p[e] = Lg[(size_t)r * 8 + e] / tau; mx = fmaxf(mx, p[e]); }
    float sum = 0.f;
#pragma unroll
    for (int e = 0; e < 8; e++) { p[e] = expf(p[e] - mx); sum += p[e]; }
#pragma unroll
    for (int e = 0; e < 8; e++) p[e] = p[e] / sum;
#pragma unroll
    for (int e = 0; e < 8; e++) p[e] = 0.85f * p[e] + 0.01875f;   // (1-ALPHA)p + ALPHA/E
    float w = 0.1f + 0.1f * tn;
    float shared_p = fmaxf(p[0], w);
    float osum = 0.f;
#pragma unroll
    for (int e = 1; e < 8; e++) osum += p[e];
    float denom_o = fmaxf(osum, 1e-8f);
    float one_m = 1.0f - shared_p;
    p[0] = shared_p;
#pragma unroll
    for (int e = 1; e < 8; e++) p[e] = (p[e] / denom_o) * one_m;  // match np op order
    int i0 = 0; float v0 = p[0];
#pragma unroll
    for (int e = 1; e < 8; e++) if (p[e] > v0) { v0 = p[e]; i0 = e; }
    int i1 = -1; float v1 = -INFINITY;
#pragma unroll
    for (int e = 0; e < 8; e++) if (e != i0 && p[e] > v1) { v1 = p[e]; i1 = e; }
    float cap = 0.5f + 0.1f * tn;
    float dsp[8], capped[8], hr[8];
    float exsum = 0.f, hsum = 0.f;
#pragma unroll
    for (int e = 0; e < 8; e++) {
        float d = ((e == i0) ? v0 : 0.f) + ((e == i1) ? v1 : 0.f);
        float ex = fmaxf(d - cap, 0.f);
        float c = d - ex;
        float hh = fmaxf(cap - c, 0.f);
        capped[e] = c; hr[e] = hh;
        exsum += ex; hsum += hh;
    }
    float hden = fmaxf(hsum, 1e-8f);
    float dsum = 0.f;
#pragma unroll
    for (int e = 0; e < 8; e++) {
        float d = capped[e] + exsum * (hr[e] / hden);
        dsp[e] = d; dsum += d;
    }
    float cden = dsum + 1e-8f;
#pragma unroll
    for (int e = 0; e < 8; e++) {
        outp[(size_t)r * 8 + e] = dsp[e];
        outp[65536 + (size_t)r * 8 + e] = dsp[e] / cden;
    }
    int lane = tid & 63, wv = tid >> 6;
#pragma unroll
    for (int e = 0; e < 8; e++) {
        double s = (double)dsp[e];
#pragma unroll
        for (int off = 1; off < 64; off <<= 1) s += __shfl_xor(s, off, 64);
        if (lane == 0) wred[wv][e] = s;
    }
    __syncthreads();
    if (tid < 8) {
        double s = wred[0][tid] + wred[1][tid] + wred[2][tid] + wred[3][tid];
        atomicAdd(&loadAcc[tid], s);
    }
}

// ----------------------------------------------------------------------------
__global__ void penalty_k(const double* __restrict__ loadAcc, float* __restrict__ outp) {
    if (threadIdx.x == 0) {
        const float thr = (float)(2048.0 / 7.0 * 1.5);  // fair * 1.5
        float pen = 0.f;
#pragma unroll
        for (int e = 1; e < 8; e++) {
            float load = (float)(loadAcc[e] / 4.0);     // mean over B
            float x = fmaxf(load - thr, 0.f);
            pen += x * x;
        }
        outp[131072] = 0.01f * pen;
    }
}

// ----------------------------------------------------------------------------
extern "C" void kernel_launch(void* const* d_in, const int* in_sizes, int n_in,
                              void* d_out, int out_size, void* d_ws, size_t ws_size,
                              hipStream_t stream)
{
    const float* tokens = (const float*)d_in[0];
    const float* outA   = (const float*)d_in[1];
    const float* outC   = (const float*)d_in[2];
    const int*   tt     = (const int*)  d_in[3];
    const float* in_w   = (const float*)d_in[4];
    const float* in_b   = (const float*)d_in[5];
    const float* op_w   = (const float*)d_in[6];
    const float* op_b   = (const float*)d_in[7];
    const float* lng    = (const float*)d_in[8];
    const float* lnb    = (const float*)d_in[9];
    const float* te_w1  = (const float*)d_in[10];
    const float* te_b1  = (const float*)d_in[11];
    const float* te_w2  = (const float*)d_in[12];
    const float* te_b2  = (const float*)d_in[13];
    const float* g_w1   = (const float*)d_in[14];
    const float* g_b1   = (const float*)d_in[15];
    const float* g_w2   = (const float*)d_in[16];
    const float* g_b2   = (const float*)d_in[17];
    const float* e_bias = (const float*)d_in[18];
    float* out = (float*)d_out;

    float* ws = (float*)d_ws;
    const size_t NM = (size_t)8192 * 1024;
    float* F0     = ws;                  // out_proj result, then gate hidden (fp32)
    float* temb   = ws + NM;             // 4x1024 fp32
    float* embb   = temb + 4096;
    float* hte    = embb + 4096;         // 4x2048
    float* logitsb = hte + 8192;         // 8192x8
    double* loads = (double*)(logitsb + 65536);   // 8 doubles (+pad)

    u16* U = (u16*)(loads + 16);
    u16* Tokh = U;                 // tokens planes (alive whole launch)
    u16* Tokl = Tokh + NM;
    u16* ActH = Tokl + NM;         // [outA;outC] planes for K/V GEMMs
    u16* ActL = ActH + NM;
    u16* Qh   = ActL + NM;         // Q planes -> attn ctx planes (block-disjoint alias)
    u16* Ql   = Qh + NM;
    u16* Kh   = Ql + NM;           // K planes -> later LN(ctx_B) planes
    u16* Kl   = Kh + NM;
    u16* Vth  = Kl + NM;           // V^T planes [b][h][d][2048]
    u16* Vtl  = Vth + NM;
    u16* Wsh  = Vtl + NM;          // weight planes (up to 3M elems)
    u16* Wsl  = Wsh + (size_t)3 * 1024 * 1024;
    u16* Tbh  = Wsl + (size_t)3 * 1024 * 1024;   // temb planes, 4096
    u16* Tbl  = Tbh + 4096;

    zero_k<<<1, 64, 0, stream>>>(loads);
    emb_k<<<4, 512, 0, stream>>>(tt, embb);
    te_fc_k<<<dim3(4, 128), 256, 0, stream>>>(embb, te_w1, te_b1, hte, 1024, 2048, 1);
    te_fc_k<<<dim3(4, 64),  256, 0, stream>>>(hte,  te_w2, te_b2, temb, 2048, 1024, 0);

    split_k<<<8192, 256, 0, stream>>>(tokens, Tokh, Tokl, 8192 * 1024 / 4);
    split_k<<<3072, 256, 0, stream>>>(in_w, Wsh, Wsl, 3 * 1024 * 1024 / 4);
    split_k<<<4096, 256, 0, stream>>>(outA, ActH, ActL, 4096 * 1024 / 4);
    split_k<<<4096, 256, 0, stream>>>(outC, ActH + (size_t)4096 * 1024,
                                      ActL + (size_t)4096 * 1024, 4096 * 1024 / 4);

    // q = tokens @ wq.T + bq -> Q planes
    bfgemm_k<false, false, 1><<<dim3(64, 8), 256, 0, stream>>>(
        Tokh, Tokl, nullptr, nullptr, nullptr, nullptr,
        Wsh, Wsl, in_b, nullptr, Qh, Ql, 1024);
    // k -> K planes with per-batch concat row remap
    bfgemm_k<false, false, 2><<<dim3(64, 8), 256, 0, stream>>>(
        ActH, ActL, nullptr, nullptr, nullptr, nullptr,
        Wsh + (size_t)1024 * 1024, Wsl + (size_t)1024 * 1024,
        in_b + 1024, nullptr, Kh, Kl, 1024);
    // v^T: operands swapped (A = wv rows, "W" = act rows) -> transposed planes
    bfgemm_k<false, false, 3><<<dim3(8, 64), 256, 0, stream>>>(
        Wsh + (size_t)2048 * 1024, Wsl + (size_t)2048 * 1024,
        nullptr, nullptr, nullptr, nullptr,
        ActH, ActL, in_b + 2048, nullptr, Vth, Vtl, 1024);

    attn_k<<<dim3(64, 8), 512, 0, stream>>>(Qh, Ql, Kh, Kl, Vth, Vtl, Qh, Ql);

    // out_proj: ctx planes (in Qh/Ql) @ op_w -> fp32 F0
    split_k<<<1024, 256, 0, stream>>>(op_w, Wsh, Wsl, 1024 * 1024 / 4);
    bfgemm_k<false, false, 0><<<dim3(64, 8), 256, 0, stream>>>(
        Qh, Ql, nullptr, nullptr, nullptr, nullptr,
        Wsh, Wsl, op_b, F0, nullptr, nullptr, 1024);

    // ctx_B = LN(out_proj + tokens) -> planes (reuse K planes)
    ln_split_k<<<8192, 256, 0, stream>>>(F0, tokens, lng, lnb, Kh, Kl);

    // gate hidden = relu([tokens | ctx_B | t_emb] @ g_w1.T + b1) -> F0
    split_k<<<4, 256, 0, stream>>>(temb, Tbh, Tbl, 4096 / 4);
    split_k<<<3072, 256, 0, stream>>>(g_w1, Wsh, Wsl, 3072 * 1024 / 4);
    bfgemm_k<true, true, 0><<<dim3(64, 8), 256, 0, stream>>>(
        Tokh, Tokl, Kh, Kl, Tbh, Tbl,
        Wsh, Wsl, g_b1, F0, nullptr, nullptr, 3072);

    logits_k<<<2048, 256, 0, stream>>>(F0, g_w2, g_b2, e_bias, logitsb);
    router_k<<<32, 256, 0, stream>>>(logitsb, tt, out, loads);
    penalty_k<<<1, 64, 0, stream>>>(loads, out);
}